// Round 7
// baseline (410.407 us; speedup 1.0000x reference)
//
#include <hip/hip_runtime.h>
#include <stdint.h>

// ---- types ----
typedef __attribute__((ext_vector_type(4))) float f32x4;
typedef __attribute__((ext_vector_type(16))) float f32x16;
typedef __attribute__((ext_vector_type(8))) short s16x8;
typedef __attribute__((ext_vector_type(4))) short s16x4;
typedef __attribute__((ext_vector_type(4))) unsigned int u32x4;
typedef __attribute__((ext_vector_type(8))) _Float16 f16x8;
typedef __attribute__((ext_vector_type(2))) _Float16 f16x2;

#define MFMA16(a, b, c) __builtin_amdgcn_mfma_f32_16x16x32_bf16((a), (b), (c), 0, 0, 0)
#define MFMA32H(a, b, c) __builtin_amdgcn_mfma_f32_32x32x16_f16((a), (b), (c), 0, 0, 0)

// B=2, T=8192, D=256; rows = B*T = 16384 flat.

__device__ __forceinline__ unsigned short f2bf(float f) {
  unsigned int u = __float_as_uint(f);
  u += 0x7FFFu + ((u >> 16) & 1u);  // RNE
  return (unsigned short)(u >> 16);
}
__device__ __forceinline__ float bf2f(unsigned short h) {
  return __uint_as_float(((unsigned int)h) << 16);
}
__device__ __forceinline__ unsigned int packh2(float a, float b) {
  f16x2 t;
  t[0] = (_Float16)a;
  t[1] = (_Float16)b;
  return *(unsigned int*)&t;
}

// ---------------- kernel 1: weight transpose + hi/lo split (bf16) -----------
__global__ void wtrans_kernel(const float* __restrict__ Wq,
                              const float* __restrict__ Wk,
                              const float* __restrict__ Wv,
                              short* __restrict__ wt) {
  int idx = blockIdx.x * 256 + threadIdx.x;   // 768 blocks * 256
  int w = idx >> 16;
  int rc = idx & 65535;
  int d = rc >> 8;
  int n = rc & 255;
  const float* Ws = (w == 0) ? Wq : ((w == 1) ? Wk : Wv);
  float v = Ws[rc];
  unsigned short hi = f2bf(v);
  unsigned short lo = f2bf(v - bf2f(hi));
  short* th = wt + w * 131072;
  th[n * 256 + d] = (short)hi;
  th[65536 + n * 256 + d] = (short)lo;
}

// ---------------- kernel 2: QKV projection (3-term bf16 MFMA) ----------------
// Outputs fp16: Qf/Kf [16384][256], Vt [2][256][8192].
__global__ __launch_bounds__(256, 2)
void qkv_kernel(const float* __restrict__ x,
                const float* __restrict__ bq,
                const float* __restrict__ bk,
                const float* __restrict__ bv,
                const short* __restrict__ wt,
                short* __restrict__ Qf, short* __restrict__ Kf,
                short* __restrict__ Vt) {
  __shared__ short X[16896];
  int tid = threadIdx.x;
  int r0 = blockIdx.x * 32;
  int bidx = r0 >> 13;
  int tl0 = r0 & 8191;
#pragma unroll
  for (int i = 0; i < 8; i++) {
    int E = i * 1024 + tid * 4;
    int r = E >> 8, col = E & 255;
    f32x4 v = *(const f32x4*)(x + (size_t)(r0 + r) * 256 + col);
    s16x4 h, lo;
#pragma unroll
    for (int j = 0; j < 4; j++) {
      unsigned short hh = f2bf(v[j]);
      h[j] = (short)hh;
      lo[j] = (short)f2bf(v[j] - bf2f(hh));
    }
    *(s16x4*)&X[r * 264 + col] = h;
    *(s16x4*)&X[8448 + r * 264 + col] = lo;
  }
  __syncthreads();

  int lane = tid & 63, wv = tid >> 6;
  int quad = lane >> 4, lq = lane & 15;

  {
    int strip = wv & 1;
    const short* WhT = wt + ((wv < 2) ? 0 : 131072);
    const short* WlT = WhT + 65536;
    f32x4 acc[16];
#pragma unroll
    for (int nt = 0; nt < 16; nt++) acc[nt] = (f32x4){0.f, 0.f, 0.f, 0.f};
    int arow = (strip * 16 + lq) * 264 + quad * 8;
#pragma unroll
    for (int c = 0; c < 8; c++) {
      s16x8 xh = *(const s16x8*)&X[arow + c * 32];
      s16x8 xl = *(const s16x8*)&X[8448 + arow + c * 32];
#pragma unroll
      for (int nt = 0; nt < 16; nt++) {
        int boff = (nt * 16 + lq) * 256 + c * 32 + quad * 8;
        s16x8 wh = *(const s16x8*)(WhT + boff);
        s16x8 wl = *(const s16x8*)(WlT + boff);
        acc[nt] = MFMA16(xh, wh, acc[nt]);
        acc[nt] = MFMA16(xl, wh, acc[nt]);
        acc[nt] = MFMA16(xh, wl, acc[nt]);
      }
    }
    const float* bias = (wv < 2) ? bq : bk;
    _Float16* Of = (_Float16*)((wv < 2) ? Qf : Kf);
#pragma unroll
    for (int nt = 0; nt < 16; nt++) {
      int col = nt * 16 + lq;
      float bb = bias[col];
#pragma unroll
      for (int r = 0; r < 4; r++) {
        int row = r0 + strip * 16 + quad * 4 + r;
        Of[row * 256 + col] = (_Float16)(acc[nt][r] + bb);
      }
    }
  }
  {
    const short* WhT = wt + 262144;
    const short* WlT = wt + 327680;
    f32x4 acc[4][2];
#pragma unroll
    for (int mt = 0; mt < 4; mt++)
#pragma unroll
      for (int nt = 0; nt < 2; nt++) acc[mt][nt] = (f32x4){0.f, 0.f, 0.f, 0.f};
#pragma unroll
    for (int c = 0; c < 8; c++) {
      int co = c * 32 + quad * 8;
      s16x8 xh0 = *(const s16x8*)&X[lq * 264 + co];
      s16x8 xl0 = *(const s16x8*)&X[8448 + lq * 264 + co];
      s16x8 xh1 = *(const s16x8*)&X[(16 + lq) * 264 + co];
      s16x8 xl1 = *(const s16x8*)&X[8448 + (16 + lq) * 264 + co];
#pragma unroll
      for (int mt = 0; mt < 4; mt++) {
        int aoff = (wv * 64 + mt * 16 + lq) * 256 + co;
        s16x8 wh = *(const s16x8*)(WhT + aoff);
        s16x8 wl = *(const s16x8*)(WlT + aoff);
        acc[mt][0] = MFMA16(wh, xh0, acc[mt][0]);
        acc[mt][0] = MFMA16(wl, xh0, acc[mt][0]);
        acc[mt][0] = MFMA16(wh, xl0, acc[mt][0]);
        acc[mt][1] = MFMA16(wh, xh1, acc[mt][1]);
        acc[mt][1] = MFMA16(wl, xh1, acc[mt][1]);
        acc[mt][1] = MFMA16(wh, xl1, acc[mt][1]);
      }
    }
#pragma unroll
    for (int mt = 0; mt < 4; mt++) {
#pragma unroll
      for (int r = 0; r < 4; r++) {
        int drow = wv * 64 + mt * 16 + quad * 4 + r;
        float bb = bv[drow];
#pragma unroll
        for (int nt = 0; nt < 2; nt++) {
          ((_Float16*)Vt)[(bidx * 256 + drow) * 8192 + tl0 + nt * 16 + lq] =
              (_Float16)(acc[mt][nt][r] + bb);
        }
      }
    }
  }
}

// ---------------- kernel 3: flash attention (fp16, dbuf, shfl-P) -----------
// 256 blocks = 128 q-tiles x 2 s-blocks (64 iters of 64 s each).
// 8 waves = 4 strips (32 q) x 2 sh (32 s). Double-buffered K/V LDS,
// ONE barrier/iter. P never touches LDS: S^T C-layout -> PV B-layout via
// half-wave shfl_xor(32) exchange of packed fp16 pairs (bit-identical to
// the old LDS round-trip).
__global__ __launch_bounds__(512, 2)
void attn_kernel(const short* __restrict__ Qf, const short* __restrict__ Kf,
                 const short* __restrict__ Vt,
                 float* __restrict__ out, float* __restrict__ O1,
                 float* __restrict__ Mlg) {
  __shared__ short sm[70656];          // 141312 B = 2 x (KL 16896 + VtL 18432)
  int tid = threadIdx.x;
  int lane = tid & 63, wv = tid >> 6;
  int lq32 = lane & 31, hh = lane >> 5, h8 = hh * 8;
  int strip = wv & 3, sh = wv >> 2;
  int blk = blockIdx.x;
  int qt = blk >> 1, sblk = blk & 1;
  int row0g = qt * 128;
  int b = row0g >> 13;
  int sbase = b * 8192 + sblk * 4096;

  // Q fragments (B-operand): q = strip*32 + lq32, k = st*16 + h8 + j
  f16x8 qf[16];
  {
    const _Float16* qrow =
        (const _Float16*)Qf + (size_t)(row0g + strip * 32 + lq32) * 256 + h8;
#pragma unroll
    for (int st = 0; st < 16; st++) qf[st] = *(const f16x8*)(qrow + st * 16);
  }
  float m_ = -__builtin_inff();
  float l_ = 0.f;
  f32x16 Oacc[8];
#pragma unroll
  for (int dt = 0; dt < 8; dt++)
#pragma unroll
    for (int i = 0; i < 16; i++) Oacc[dt][i] = 0.f;

  // stage tile 0: global -> regs -> buf0
  u32x4 k_r[4], vt_r[4];
#pragma unroll
  for (int i = 0; i < 4; i++) {
    int L = i * 512 + tid;
    int s = L >> 5, g = L & 31;
    int d = L >> 3, g2 = L & 7;
    k_r[i] = *(const u32x4*)(Kf + (size_t)(sbase + s) * 256 + g * 8);
    vt_r[i] = *(const u32x4*)(Vt + (size_t)(b * 256 + d) * 8192 +
                              sblk * 4096 + g2 * 8);
  }
#pragma unroll
  for (int i = 0; i < 4; i++) {
    int L = i * 512 + tid;
    int s = L >> 5, g = L & 31;
    int d = L >> 3, g2 = L & 7;
    *(u32x4*)&sm[s * 264 + g * 8] = k_r[i];
    *(u32x4*)&sm[16896 + d * 72 + g2 * 8] = vt_r[i];
  }

  for (int it = 0; it < 64; it++) {
    short* cur = sm + (it & 1) * 35328;
    __syncthreads();                   // cur buffer ready for all waves
    // issue global prefetch of tile it+1 (in flight across the compute)
    if (it < 63) {
      int s0n = (it + 1) * 64;
#pragma unroll
      for (int i = 0; i < 4; i++) {
        int L = i * 512 + tid;
        int s = L >> 5, g = L & 31;
        int d = L >> 3, g2 = L & 7;
        k_r[i] = *(const u32x4*)(Kf + (size_t)(sbase + s0n + s) * 256 + g * 8);
        vt_r[i] = *(const u32x4*)(Vt + (size_t)(b * 256 + d) * 8192 +
                                  sblk * 4096 + s0n + g2 * 8);
      }
    }
    // S^T = K Q^T over wave's 32 s x 32 q (single-term fp16)
    f32x16 sacc;
#pragma unroll
    for (int i = 0; i < 16; i++) sacc[i] = 0.f;
    int krow = (sh * 32 + lq32) * 264 + h8;
#pragma unroll
    for (int st = 0; st < 16; st++) {
      f16x8 kf = *(const f16x8*)&cur[krow + st * 16];
      sacc = MFMA32H(kf, qf[st], sacc);
    }
    // in-lane online softmax (16 regs + partner half-wave)
    float mx = sacc[0];
#pragma unroll
    for (int i = 1; i < 16; i++) mx = fmaxf(mx, sacc[i]);
    mx = fmaxf(mx, __shfl_xor(mx, 32));
    float mn = fmaxf(m_, mx);
    float alpha = __expf(m_ - mn);
    m_ = mn;
    float rs = 0.f;
#pragma unroll
    for (int i = 0; i < 16; i++) {
      sacc[i] = __expf(sacc[i] - mn);
      rs += sacc[i];
    }
    rs += __shfl_xor(rs, 32);
    l_ = l_ * alpha + rs;
    // pack P to fp16 pairs: pkk[g*2+jp] holds s = 8g + 4hh + {2jp, 2jp+1}
    unsigned int pkk[8], pxx[8];
#pragma unroll
    for (int g = 0; g < 4; g++) {
#pragma unroll
      for (int jp = 0; jp < 2; jp++)
        pkk[g * 2 + jp] = packh2(sacc[4 * g + 2 * jp], sacc[4 * g + 2 * jp + 1]);
    }
#pragma unroll
    for (int i = 0; i < 8; i++) pxx[i] = (unsigned int)__shfl_xor((int)pkk[i], 32);
    // build PV B-frags: chunk c needs k = 16c + 8hh + i
    u32x4 F0, F1;
    F0[0] = hh ? pxx[2] : pkk[0];
    F0[1] = hh ? pxx[3] : pkk[1];
    F0[2] = hh ? pkk[2] : pxx[0];
    F0[3] = hh ? pkk[3] : pxx[1];
    F1[0] = hh ? pxx[6] : pkk[4];
    F1[1] = hh ? pxx[7] : pkk[5];
    F1[2] = hh ? pkk[6] : pxx[4];
    F1[3] = hh ? pkk[7] : pxx[5];
    f16x8 pf0 = *(f16x8*)&F0;
    f16x8 pf1 = *(f16x8*)&F1;
    // rescale O^T (in-lane per q); skip when wave-uniform no-op
    if (!__all(alpha == 1.f)) {
#pragma unroll
      for (int dt = 0; dt < 8; dt++) Oacc[dt] = Oacc[dt] * alpha;
    }
    // O^T += V P^T
    const short* vb = cur + 16896;
#pragma unroll
    for (int dt = 0; dt < 8; dt++) {
      int vrow = (dt * 32 + lq32) * 72 + sh * 32;
      f16x8 vf0 = *(const f16x8*)&vb[vrow + h8];
      f16x8 vf1 = *(const f16x8*)&vb[vrow + 16 + h8];
      Oacc[dt] = MFMA32H(vf0, pf0, Oacc[dt]);
      Oacc[dt] = MFMA32H(vf1, pf1, Oacc[dt]);
    }
    // commit prefetched tile it+1 into the other buffer (no barrier here:
    // everyone finished reading it during iter it-1, guaranteed by the
    // barrier at the top of THIS iter)
    if (it < 63) {
      short* nxt = sm + ((it + 1) & 1) * 35328;
#pragma unroll
      for (int i = 0; i < 4; i++) {
        int L = i * 512 + tid;
        int s = L >> 5, g = L & 31;
        int d = L >> 3, g2 = L & 7;
        *(u32x4*)&nxt[s * 264 + g * 8] = k_r[i];
        *(u32x4*)&nxt[16896 + d * 72 + g2 * 8] = vt_r[i];
      }
    }
  }

  // ---- epilogue: sh pair-merge + coalesced partial write ----
  // Scratch (68.7 KB) sits in buf0; final iter's reads hit buf1 -> no race.
  float* smf = (float*)sm;             // Ob: 4 strips x [32 q][132] f32
  float* Msh = smf + 16896;            // m [2][4][32], l at +256
  if (lane < 32) {
    Msh[(sh * 4 + strip) * 32 + lq32] = m_;
    Msh[256 + (sh * 4 + strip) * 32 + lq32] = l_;
  }
  __syncthreads();
  float m1 = Msh[((1 - sh) * 4 + strip) * 32 + lq32];
  float l1 = Msh[256 + ((1 - sh) * 4 + strip) * 32 + lq32];
  float mm = fmaxf(m_, m1);
  float e0 = __expf(m_ - mm);
  float e1 = __expf(m1 - mm);
  float* Opart = (sblk == 0) ? out : O1;
  if (sh == 0 && lane < 32) {          // combined (m, l) for this s-block
    float lsum = l_ * e0 + l1 * e1;
    int rowq = row0g + strip * 32 + lq32;
    Mlg[sblk * 32768 + rowq * 2] = mm;
    Mlg[sblk * 32768 + rowq * 2 + 1] = lsum;
  }
  float* Ob = smf + strip * 4224;      // 32*132
#pragma unroll
  for (int hd = 0; hd < 2; hd++) {
    __syncthreads();
    if (sh == 1) {
#pragma unroll
      for (int dt2 = 0; dt2 < 4; dt2++) {
        int dt = hd * 4 + dt2;
#pragma unroll
        for (int g = 0; g < 4; g++) {
          f32x4 v = {Oacc[dt][g * 4], Oacc[dt][g * 4 + 1],
                     Oacc[dt][g * 4 + 2], Oacc[dt][g * 4 + 3]};
          *(f32x4*)&Ob[lq32 * 132 + dt2 * 32 + 8 * g + 4 * hh] = v;
        }
      }
    }
    __syncthreads();
    if (sh == 0) {
#pragma unroll
      for (int dt2 = 0; dt2 < 4; dt2++) {
        int dt = hd * 4 + dt2;
#pragma unroll
        for (int g = 0; g < 4; g++) {
          float* ad = &Ob[lq32 * 132 + dt2 * 32 + 8 * g + 4 * hh];
          f32x4 o1 = *(f32x4*)ad;
          f32x4 cmb;
#pragma unroll
          for (int j = 0; j < 4; j++)
            cmb[j] = Oacc[dt][g * 4 + j] * e0 + o1[j] * e1;
          *(f32x4*)ad = cmb;
        }
      }
    }
    __syncthreads();
    // cooperative coalesced write of this d-half: 128 q x 32 f32x4 groups
#pragma unroll
    for (int i = 0; i < 8; i++) {
      int idx = i * 512 + tid;
      int q = idx >> 5, gb = idx & 31;
      f32x4 v = *(f32x4*)&smf[(q >> 5) * 4224 + (q & 31) * 132 + gb * 4];
      *(f32x4*)&Opart[(size_t)(row0g + q) * 256 + hd * 128 + gb * 4] = v;
    }
  }
}

// ---------------- kernel 4: s-split merge ----------------
__global__ void merge_kernel(const float* __restrict__ O1,
                             const float* __restrict__ Mlg,
                             float* __restrict__ out) {
  int idx = blockIdx.x * 256 + threadIdx.x;   // 4096 blocks
  int q = idx >> 6, dg = idx & 63;
  float m0 = Mlg[q * 2], l0 = Mlg[q * 2 + 1];
  float m1 = Mlg[32768 + q * 2], l1 = Mlg[32768 + q * 2 + 1];
  float mm = fmaxf(m0, m1);
  float e0 = __expf(m0 - mm), e1 = __expf(m1 - mm);
  float inv = 1.f / (l0 * e0 + l1 * e1);
  f32x4 a = *(const f32x4*)(out + (size_t)q * 256 + dg * 4);
  f32x4 bb = *(const f32x4*)(O1 + (size_t)q * 256 + dg * 4);
  f32x4 r;
#pragma unroll
  for (int j = 0; j < 4; j++) r[j] = (a[j] * e0 + bb[j] * e1) * inv;
  *(f32x4*)(out + (size_t)q * 256 + dg * 4) = r;
}

// ---------------- launcher ----------------
extern "C" void kernel_launch(void* const* d_in, const int* in_sizes, int n_in,
                              void* d_out, int out_size, void* d_ws, size_t ws_size,
                              hipStream_t stream) {
  const float* x  = (const float*)d_in[0];
  const float* Wq = (const float*)d_in[1];
  const float* bq = (const float*)d_in[2];
  const float* Wk = (const float*)d_in[3];
  const float* bk = (const float*)d_in[4];
  const float* Wv = (const float*)d_in[5];
  const float* bv = (const float*)d_in[6];
  float* out = (float*)d_out;
  short* ws = (short*)d_ws;
  // ws layout (shorts): wt 393216 | Qf 4194304 | Kf 4194304 | Vt 4194304 |
  // O1 (float 4194304) at short-offset 12976128. Mlg aliases wt (dead after
  // qkv).
  short* wt = ws;
  short* Qf = ws + 393216;
  short* Kf = Qf + 4194304;
  short* Vt = Kf + 4194304;
  float* O1  = (float*)(ws + 12976128);
  float* Mlg = (float*)ws;
  hipLaunchKernelGGL(wtrans_kernel, dim3(768), dim3(256), 0, stream, Wq, Wk, Wv, wt);
  hipLaunchKernelGGL(qkv_kernel, dim3(512), dim3(256), 0, stream,
                     x, bq, bk, bv, wt, Qf, Kf, Vt);
  hipLaunchKernelGGL(attn_kernel, dim3(256), dim3(512), 0, stream,
                     Qf, Kf, Vt, out, O1, Mlg);
  hipLaunchKernelGGL(merge_kernel, dim3(4096), dim3(256), 0, stream,
                     O1, Mlg, out);
}